// Round 4
// baseline (23.587 us; speedup 1.0000x reference)
//
#include <hip/hip_runtime.h>

// TBSyntaxParser v4: single fused kernel, B-fragments loaded straight from W1
// into registers (no prep kernel, no d_ws), gather indices computed per-thread
// (no first barrier), v_perm-packed bf16 conversion.
// B=4096, L=128, D=60, X=360(k, pad 384), HID=200(n, pad 208), OUT=3.
// d_out = [out (B*3) | legal (B*3)] f32.

#define Bq    4096
#define Lq    128
#define Dq    60
#define HIDq  200
#define ONUM  3
#define KTN   12      // k-tiles (384/32)
#define MB    16      // states per block (MFMA M)
#define NTHR  512     // 8 waves

typedef short bf16x8 __attribute__((ext_vector_type(8)));
typedef float f32x4  __attribute__((ext_vector_type(4)));

union BF8 { int u[4]; bf16x8 v; };

__device__ __forceinline__ unsigned int rhu(float f) {
    union { float f; unsigned int u; } x; x.f = f;
    return x.u + 0x8000u;                      // round-half-up into bf16 slot
}
// pack two rounded floats -> (bf16(hi)<<16) | bf16(lo) in one v_perm_b32
__device__ __forceinline__ int pack2(float lo, float hi) {
    return (int)__builtin_amdgcn_perm(rhu(hi), rhu(lo), 0x07060302u);
}

__global__ __launch_bounds__(NTHR, 2) void parser_fused(
    const float* __restrict__ buffer,
    const float* __restrict__ W1,
    const float* __restrict__ b1,
    const float* __restrict__ W2,
    const float* __restrict__ b2,
    const int*   __restrict__ buffer_index,
    const int*   __restrict__ stack_indexes,
    const int*   __restrict__ stack_len,
    float*       __restrict__ out)
{
    __shared__ unsigned short Afrag[KTN * 64 * 8];   // 12 KiB, A-fragment packed
    __shared__ float psum[8][MB][ONUM];              // 1.5 KiB wave partials

    const int t  = threadIdx.x;
    const int w  = t >> 6;
    const int l  = t & 63;
    const int s0 = blockIdx.x * MB;

    // ---- gather X: 1440 float4 jobs over 512 threads (2 or 3 each, static) ----
    // X[s][k] -> kt=k>>5, lane = s + ((k&31)>>3)*16, e = k&7  (k0%4==0 per job)
    #define GATHER_JOB(i)                                                        \
    {                                                                            \
        int s = (i) / 90, r = (i) % 90, seg = r / 15, f = r % 15;                \
        int row = (seg < 3) ? (buffer_index[s0 + s] + seg)                       \
                            : stack_indexes[(s0 + s) * 3 + (seg - 3)];           \
        float4 v = ((const float4*)(buffer + ((size_t)(s0 + s) * Lq + row) * Dq))[f]; \
        int k0   = seg * 60 + f * 4;                                             \
        int kt   = k0 >> 5;                                                      \
        int lane = s + (((k0 & 31) >> 3) << 4);                                  \
        uint2 pk;                                                                \
        pk.x = (unsigned)pack2(v.x, v.y);                                        \
        pk.y = (unsigned)pack2(v.z, v.w);                                        \
        *((uint2*)&Afrag[(size_t)(kt * 64 + lane) * 8 + (k0 & 7)]) = pk;         \
    }
    GATHER_JOB(t)
    GATHER_JOB(t + 512)
    if (t < 416) GATHER_JOB(t + 1024)
    #undef GATHER_JOB

    // zero k-pad of kt=11 (lanes 16..63 hold k in [360,384))
    if (t < 48) {
        f32x4 z = {0.f, 0.f, 0.f, 0.f};
        *((f32x4*)&Afrag[(size_t)(11 * 64 + 16 + t) * 8]) = z;
    }

    // ---- B-fragments straight from W1 into registers ----
    // lane l holds W1[k = kt*32 + (l>>4)*8 + e][n = nt*16 + (l&15)]
    const int  nt0   = w;
    const int  n0    = nt0 * 16 + (l & 15);          // <= 127, always valid
    const bool hasB1 = (w < 5);
    const int  n1    = (8 + w) * 16 + (l & 15);      // may exceed 199 for w==4
    const bool n1ok  = n1 < HIDq;
    const int  kb    = (l >> 4) * 8;

    BF8 B0[KTN], B1[KTN];
    #pragma unroll
    for (int kt = 0; kt < KTN; ++kt) {
        #pragma unroll
        for (int j = 0; j < 4; ++j) {
            int k0 = kt * 32 + kb + 2 * j;
            float lo0 = (k0     < 360) ? W1[(size_t)k0       * HIDq + n0] : 0.f;
            float hi0 = (k0 + 1 < 360) ? W1[(size_t)(k0 + 1) * HIDq + n0] : 0.f;
            B0[kt].u[j] = pack2(lo0, hi0);
            if (hasB1) {
                float lo1 = (k0     < 360 && n1ok) ? W1[(size_t)k0       * HIDq + n1] : 0.f;
                float hi1 = (k0 + 1 < 360 && n1ok) ? W1[(size_t)(k0 + 1) * HIDq + n1] : 0.f;
                B1[kt].u[j] = pack2(lo1, hi1);
            }
        }
    }

    // ---- prefetch epilogue constants ----
    float bb0 = b1[n0];
    float w20 = W2[n0 * ONUM + 0], w21 = W2[n0 * ONUM + 1], w22 = W2[n0 * ONUM + 2];
    float bb1 = 0.f, w23 = 0.f, w24 = 0.f, w25 = 0.f;
    if (hasB1 && n1ok) {
        bb1 = b1[n1];
        w23 = W2[n1 * ONUM + 0]; w24 = W2[n1 * ONUM + 1]; w25 = W2[n1 * ONUM + 2];
    }

    // ---- legal mask (independent of MLP) ----
    if (t < MB * ONUM) {
        int s = t / ONUM, o = t % ONUM;
        int bi = buffer_index[s0 + s];
        int sl = stack_len[s0 + s];
        float lg;
        if (o == 0)      lg = (bi + 3 >= Lq) ? 0.f : 1.f;
        else if (o == 1) lg = (sl <= 3)      ? 0.f : 1.f;
        else             lg = (sl <= 4)      ? 0.f : 1.f;
        out[(size_t)Bq * ONUM + (size_t)(s0 + s) * ONUM + o] = lg;
    }
    __syncthreads();

    // ---- layer 1 MFMA: wave w owns n-tiles {w, 8+w (if w<5)} ----
    f32x4 acc0 = {}, acc1 = {};
    #pragma unroll
    for (int kt = 0; kt < KTN; ++kt) {
        bf16x8 a = *((const bf16x8*)&Afrag[(size_t)(kt * 64 + l) * 8]);
        acc0 = __builtin_amdgcn_mfma_f32_16x16x32_bf16(a, B0[kt].v, acc0, 0, 0, 0);
        if (hasB1)
            acc1 = __builtin_amdgcn_mfma_f32_16x16x32_bf16(a, B1[kt].v, acc1, 0, 0, 0);
    }

    // ---- fused epilogue: bias + ReLU + layer-2 partials in-register ----
    // lane holds hid_pre[s = (l>>4)*4 + r][j = nt*16 + (l&15)] in acc[r]
    float p[ONUM][4];
    #pragma unroll
    for (int o = 0; o < ONUM; ++o)
        #pragma unroll
        for (int r = 0; r < 4; ++r) p[o][r] = 0.f;

    #pragma unroll
    for (int r = 0; r < 4; ++r) {
        float h = acc0[r] + bb0; h = h > 0.f ? h : 0.f;
        p[0][r] = fmaf(h, w20, p[0][r]);
        p[1][r] = fmaf(h, w21, p[1][r]);
        p[2][r] = fmaf(h, w22, p[2][r]);
    }
    if (hasB1) {
        #pragma unroll
        for (int r = 0; r < 4; ++r) {
            float h = acc1[r] + bb1; h = h > 0.f ? h : 0.f;   // bb1/w2x are 0 if n1>=200
            p[0][r] = fmaf(h, w23, p[0][r]);
            p[1][r] = fmaf(h, w24, p[1][r]);
            p[2][r] = fmaf(h, w25, p[2][r]);
        }
    }

    // butterfly-reduce over the 16-lane j-group
    #pragma unroll
    for (int d = 1; d < 16; d <<= 1) {
        #pragma unroll
        for (int o = 0; o < ONUM; ++o)
            #pragma unroll
            for (int r = 0; r < 4; ++r)
                p[o][r] += __shfl_xor(p[o][r], d, 64);
    }
    if ((l & 15) == 0) {
        #pragma unroll
        for (int r = 0; r < 4; ++r) {
            int s = ((l >> 4) << 2) + r;
            #pragma unroll
            for (int o = 0; o < ONUM; ++o) psum[w][s][o] = p[o][r];
        }
    }
    __syncthreads();

    // ---- combine 8 wave-partials + bias ----
    if (t < MB * ONUM) {
        int s = t / ONUM, o = t % ONUM;
        float v = b2[o];
        #pragma unroll
        for (int w8 = 0; w8 < 8; ++w8) v += psum[w8][s][o];
        out[(size_t)(s0 + s) * ONUM + o] = v;
    }
}

extern "C" void kernel_launch(void* const* d_in, const int* in_sizes, int n_in,
                              void* d_out, int out_size, void* d_ws, size_t ws_size,
                              hipStream_t stream) {
    const float* buffer        = (const float*)d_in[0];
    const float* W1            = (const float*)d_in[1];
    const float* b1            = (const float*)d_in[2];
    const float* W2            = (const float*)d_in[3];
    const float* b2            = (const float*)d_in[4];
    const int*   buffer_index  = (const int*)d_in[5];
    const int*   stack_indexes = (const int*)d_in[6];
    const int*   stack_len     = (const int*)d_in[7];
    float*       out           = (float*)d_out;

    parser_fused<<<Bq / MB, NTHR, 0, stream>>>(
        buffer, W1, b1, W2, b2, buffer_index, stack_indexes, stack_len, out);
}

// Round 5
// 15.500 us; speedup vs baseline: 1.5217x; 1.5217x over previous
//
#include <hip/hip_runtime.h>

// TBSyntaxParser v5: two kernels (prep packs W1 -> bf16 B-fragments in d_ws;
// main does gather + MFMA + fused layer-2). Main prefetches ALL B-fragments
// into registers BEFORE the gather barrier so B-load latency overlaps gather.
// B=4096, L=128, D=60, X=360(k, pad 384), HID=200(n, pad 208), OUT=3.
// d_out = [out (B*3) | legal (B*3)] f32.

#define Bq    4096
#define Lq    128
#define Dq    60
#define HIDq  200
#define ONUM  3
#define KTN   12      // k-tiles (384/32)
#define NTN   13      // n-tiles (208/16)
#define MB    16      // states per block (MFMA M)
#define NTHR  512     // 8 waves

typedef short bf16x8 __attribute__((ext_vector_type(8)));
typedef float f32x4  __attribute__((ext_vector_type(4)));

__device__ __forceinline__ unsigned int rhu(float f) {
    union { float f; unsigned int u; } x; x.f = f;
    return x.u + 0x8000u;                      // round-half-up into bf16 slot
}
// pack two rounded floats -> (bf16(hi)<<16) | bf16(lo) in one v_perm_b32
__device__ __forceinline__ int pack2(float lo, float hi) {
    return (int)__builtin_amdgcn_perm(rhu(hi), rhu(lo), 0x07060302u);
}

// ---- prep: W1 [360][200] f32 -> B-fragment-packed bf16 in ws ----
// bfrag[((kt*NTN+nt)*64 + lane)*8 + e] = bf16(W1[kt*32+(lane>>4)*8+e][nt*16+(lane&15)])
__global__ __launch_bounds__(256) void prep_w1(const float* __restrict__ W1,
                                               unsigned short* __restrict__ bfrag) {
    int fid = blockIdx.x * 4 + (threadIdx.x >> 6);   // 39*4 = 156 fragment tiles
    int kt  = fid / NTN, nt = fid % NTN;
    int l   = threadIdx.x & 63;
    int kb  = kt * 32 + (l >> 4) * 8;
    int n   = nt * 16 + (l & 15);
    bf16x8 pack;
    #pragma unroll
    for (int e = 0; e < 8; ++e) {
        int k = kb + e;
        float f = (k < 360 && n < HIDq) ? W1[k * HIDq + n] : 0.f;
        pack[e] = (short)(unsigned short)(rhu(f) >> 16);
    }
    *((bf16x8*)(bfrag + ((size_t)fid * 64 + l) * 8)) = pack;
}

__global__ __launch_bounds__(NTHR, 2) void parser_main(
    const float* __restrict__ buffer,
    const unsigned short* __restrict__ bfrag,
    const float* __restrict__ b1,
    const float* __restrict__ W2,
    const float* __restrict__ b2,
    const int*   __restrict__ buffer_index,
    const int*   __restrict__ stack_indexes,
    const int*   __restrict__ stack_len,
    float*       __restrict__ out)
{
    __shared__ unsigned short Afrag[KTN * 64 * 8];   // 12 KiB, A-fragment packed
    __shared__ float psum[8][MB][ONUM];              // 1.5 KiB wave partials

    const int t  = threadIdx.x;
    const int w  = t >> 6;
    const int l  = t & 63;
    const int s0 = blockIdx.x * MB;

    // ---- B-fragment prefetch: 24 coalesced 16B loads, in flight during gather ----
    const int  nt0   = w;
    const int  n0    = nt0 * 16 + (l & 15);          // <= 127, always valid
    const bool hasB1 = (w < 5);
    const int  n1    = (8 + w) * 16 + (l & 15);
    const bool n1ok  = n1 < HIDq;

    bf16x8 B0[KTN], B1[KTN];
    #pragma unroll
    for (int kt = 0; kt < KTN; ++kt)
        B0[kt] = *((const bf16x8*)(bfrag + ((size_t)(kt * NTN + nt0) * 64 + l) * 8));
    if (hasB1) {
        #pragma unroll
        for (int kt = 0; kt < KTN; ++kt)
            B1[kt] = *((const bf16x8*)(bfrag + ((size_t)(kt * NTN + 8 + w) * 64 + l) * 8));
    }

    // ---- epilogue constants, also pre-barrier ----
    float bb0 = b1[n0];
    float w20 = W2[n0 * ONUM + 0], w21 = W2[n0 * ONUM + 1], w22 = W2[n0 * ONUM + 2];
    float bb1 = 0.f, w23 = 0.f, w24 = 0.f, w25 = 0.f;
    if (hasB1 && n1ok) {
        bb1 = b1[n1];
        w23 = W2[n1 * ONUM + 0]; w24 = W2[n1 * ONUM + 1]; w25 = W2[n1 * ONUM + 2];
    }

    // ---- gather X: 1440 float4 jobs over 512 threads ----
    // X[s][k] -> kt=k>>5, lane = s + ((k&31)>>3)*16, e = k&7  (k0%4==0 per job)
    #define GATHER_JOB(i)                                                        \
    {                                                                            \
        int s = (i) / 90, r = (i) % 90, seg = r / 15, f = r % 15;                \
        int row = (seg < 3) ? (buffer_index[s0 + s] + seg)                       \
                            : stack_indexes[(s0 + s) * 3 + (seg - 3)];           \
        float4 v = ((const float4*)(buffer + ((size_t)(s0 + s) * Lq + row) * Dq))[f]; \
        int k0   = seg * 60 + f * 4;                                             \
        int kt   = k0 >> 5;                                                      \
        int lane = s + (((k0 & 31) >> 3) << 4);                                  \
        uint2 pk;                                                                \
        pk.x = (unsigned)pack2(v.x, v.y);                                        \
        pk.y = (unsigned)pack2(v.z, v.w);                                        \
        *((uint2*)&Afrag[(size_t)(kt * 64 + lane) * 8 + (k0 & 7)]) = pk;         \
    }
    GATHER_JOB(t)
    GATHER_JOB(t + 512)
    if (t < 416) GATHER_JOB(t + 1024)
    #undef GATHER_JOB

    // zero k-pad of kt=11 (lanes 16..63 hold k in [360,384))
    if (t < 48) {
        f32x4 z = {0.f, 0.f, 0.f, 0.f};
        *((f32x4*)&Afrag[(size_t)(11 * 64 + 16 + t) * 8]) = z;
    }

    // ---- legal mask (independent of MLP) ----
    if (t < MB * ONUM) {
        int s = t / ONUM, o = t % ONUM;
        int bi = buffer_index[s0 + s];
        int sl = stack_len[s0 + s];
        float lg;
        if (o == 0)      lg = (bi + 3 >= Lq) ? 0.f : 1.f;
        else if (o == 1) lg = (sl <= 3)      ? 0.f : 1.f;
        else             lg = (sl <= 4)      ? 0.f : 1.f;
        out[(size_t)Bq * ONUM + (size_t)(s0 + s) * ONUM + o] = lg;
    }
    __syncthreads();

    // ---- layer 1 MFMA: A from LDS, B already in registers ----
    f32x4 acc0 = {}, acc1 = {};
    #pragma unroll
    for (int kt = 0; kt < KTN; ++kt) {
        bf16x8 a = *((const bf16x8*)&Afrag[(size_t)(kt * 64 + l) * 8]);
        acc0 = __builtin_amdgcn_mfma_f32_16x16x32_bf16(a, B0[kt], acc0, 0, 0, 0);
        if (hasB1)
            acc1 = __builtin_amdgcn_mfma_f32_16x16x32_bf16(a, B1[kt], acc1, 0, 0, 0);
    }

    // ---- fused epilogue: bias + ReLU + layer-2 partials in-register ----
    // lane holds hid_pre[s = (l>>4)*4 + r][j = nt*16 + (l&15)] in acc[r]
    float p[ONUM][4];
    #pragma unroll
    for (int o = 0; o < ONUM; ++o)
        #pragma unroll
        for (int r = 0; r < 4; ++r) p[o][r] = 0.f;

    #pragma unroll
    for (int r = 0; r < 4; ++r) {
        float h = acc0[r] + bb0; h = h > 0.f ? h : 0.f;
        p[0][r] = fmaf(h, w20, p[0][r]);
        p[1][r] = fmaf(h, w21, p[1][r]);
        p[2][r] = fmaf(h, w22, p[2][r]);
    }
    if (hasB1) {
        #pragma unroll
        for (int r = 0; r < 4; ++r) {
            float h = acc1[r] + bb1; h = h > 0.f ? h : 0.f;   // consts are 0 if n1>=200
            p[0][r] = fmaf(h, w23, p[0][r]);
            p[1][r] = fmaf(h, w24, p[1][r]);
            p[2][r] = fmaf(h, w25, p[2][r]);
        }
    }

    // butterfly-reduce over the 16-lane j-group
    #pragma unroll
    for (int d = 1; d < 16; d <<= 1) {
        #pragma unroll
        for (int o = 0; o < ONUM; ++o)
            #pragma unroll
            for (int r = 0; r < 4; ++r)
                p[o][r] += __shfl_xor(p[o][r], d, 64);
    }
    if ((l & 15) == 0) {
        #pragma unroll
        for (int r = 0; r < 4; ++r) {
            int s = ((l >> 4) << 2) + r;
            #pragma unroll
            for (int o = 0; o < ONUM; ++o) psum[w][s][o] = p[o][r];
        }
    }
    __syncthreads();

    // ---- combine 8 wave-partials + bias ----
    if (t < MB * ONUM) {
        int s = t / ONUM, o = t % ONUM;
        float v = b2[o];
        #pragma unroll
        for (int w8 = 0; w8 < 8; ++w8) v += psum[w8][s][o];
        out[(size_t)(s0 + s) * ONUM + o] = v;
    }
}

extern "C" void kernel_launch(void* const* d_in, const int* in_sizes, int n_in,
                              void* d_out, int out_size, void* d_ws, size_t ws_size,
                              hipStream_t stream) {
    const float* buffer        = (const float*)d_in[0];
    const float* W1            = (const float*)d_in[1];
    const float* b1            = (const float*)d_in[2];
    const float* W2            = (const float*)d_in[3];
    const float* b2            = (const float*)d_in[4];
    const int*   buffer_index  = (const int*)d_in[5];
    const int*   stack_indexes = (const int*)d_in[6];
    const int*   stack_len     = (const int*)d_in[7];
    float*       out           = (float*)d_out;

    unsigned short* bfrag = (unsigned short*)d_ws;   // 156*64*8*2 = 159,744 B

    prep_w1<<<39, 256, 0, stream>>>(W1, bfrag);
    parser_main<<<Bq / MB, NTHR, 0, stream>>>(
        buffer, bfrag, b1, W2, b2, buffer_index, stack_indexes, stack_len, out);
}